// Round 5
// baseline (550.768 us; speedup 1.0000x reference)
//
#include <hip/hip_runtime.h>
#include <hip/hip_fp16.h>

// Native vector types: clang's __builtin_nontemporal_load/store only accept
// scalar/vector types, not HIP's struct float4.
typedef float        __attribute__((ext_vector_type(2))) f32x2;
typedef float        __attribute__((ext_vector_type(4))) f32x4;
typedef int          __attribute__((ext_vector_type(4))) i32x4;
typedef unsigned int __attribute__((ext_vector_type(4))) u32x4;

// Problem constants (from reference)
constexpr int Hdim = 1024;
constexpr int Wdim = 1024;
constexpr int HWp  = Hdim * Wdim;     // 1,048,576 pixels
constexpr int Kp   = 24;              // composite layers
constexpr int KSp  = 50;              // shadow layers
constexpr int Cp   = 14;              // feature channels
constexpr int Np   = 500000;          // points

constexpr int SHD_BLOCKS = HWp / 4 / 256;   // 1024 shadow blocks
constexpr int IMG_BLOCKS = HWp / 256;       // 4096 image blocks

// Early-exit transmittance cutoff. Remaining weights telescope to <= T and
// features are in [0,1), so per-channel truncation error <= TCUT.
// Empirical error model (3 rounds, exact): absmax = TCUT + 2^-8 (harness
// compare is quantized at 2^-8). 8e-3 -> 0.0117 measured, tolerance 2e-2.
// 1.2e-2 would leave only 22% margin for ~5 us -> rejected.
#define TCUT 8e-3f

__device__ __forceinline__ unsigned pack2(float lo, float hi)
{
    __half2 h = __halves2half2(__float2half_rn(lo), __float2half_rn(hi));
    unsigned u; __builtin_memcpy(&u, &h, 4); return u;
}
__device__ __forceinline__ void unpack2(unsigned u, float& lo, float& hi)
{
    __half2 h; __builtin_memcpy(&h, &u, 4);
    lo = __low2float(h); hi = __high2float(h);
}

// ---- Pre-pass: features (N x 14 f32) -> u8 + fp16 1/r^2 in 16 B rows ------
// Gather table: 8 MB. 4 MB L2/XCD covers half -> ~50% L2 hit on random
// gathers (measured: R1's 16 MB table hit exactly the 4/16 capacity ratio,
// 64 B line granularity confirmed by bytes/gather arithmetic; L3 absorbs
// ~nothing). 8 B rows (full L2 residency) would need <=5-bit features ->
// error >= 0.016, over the budget. This is the table-size floor.
// Row layout (16 B): bytes 0..13 = u8 features (f = u8/255), bytes 14..15
// = fp16(1/r^2).
__global__ __launch_bounds__(256) void repack_k(
    const f32x2* __restrict__ feat2,   // N*7 float2 (56 B rows, 8B-aligned)
    const float* __restrict__ rad,     // N f32
    u32x4* __restrict__ ws)            // N u32x4 (16 B rows)
{
    int i = blockIdx.x * 256 + threadIdx.x;
    if (i >= Np) return;
    const f32x2* s = feat2 + (long long)i * 7;
    unsigned q[14];
#pragma unroll
    for (int j = 0; j < 7; ++j) {
        f32x2 v = __builtin_nontemporal_load(s + j);   // streamed once
        q[2 * j]     = (unsigned)(v.x * 255.0f + 0.5f);  // f in [0,1): exact rn
        q[2 * j + 1] = (unsigned)(v.y * 255.0f + 0.5f);
    }
    float r   = rad[i];
    float inv = 1.0f / (r * r);
    u32x4 w;
    w.x = q[0]  | (q[1]  << 8) | (q[2]  << 16) | (q[3]  << 24);
    w.y = q[4]  | (q[5]  << 8) | (q[6]  << 16) | (q[7]  << 24);
    w.z = q[8]  | (q[9]  << 8) | (q[10] << 16) | (q[11] << 24);
    w.w = q[12] | (q[13] << 8) | ((pack2(inv, 0.0f) & 0xffffu) << 16);
    ws[i] = w;
}

// ---- Fused kernel: blocks [0,SHD_BLOCKS) = shadow visibility (stream-rate
// traffic, independent of image), blocks [SHD_BLOCKS, +IMG_BLOCKS) = image
// composite. image_k alone runs at ~3.5 TB/s (random-gather-limited, channel
// headroom unused); interleaving shadow's streaming fills that headroom
// instead of paying ~12 us serially. Shadow scheduled first (low blockIdx)
// so its traffic mixes in from ramp-up. All deps (memset of vis, repack)
// are earlier launches on the same stream.
template <bool PACKED>
__global__ __launch_bounds__(256) void fused_k(
    const int*   __restrict__ idx,     // (K, H, W) int32
    const float* __restrict__ d2s,     // (K, H, W) f32
    const u32x4* __restrict__ packed,  // N u32x4 (PACKED path)
    const f32x2* __restrict__ feat2,   // N*7 float2 (fallback path)
    const float* __restrict__ rad,     // N f32      (fallback path)
    float* __restrict__ out,           // (H, W, C) f32
    const i32x4* __restrict__ sidx4,   // (KS, HW/4) int4
    const f32x4* __restrict__ zb4,     // (KS, HW/4) float4
    float* __restrict__ vis)           // N f32 (pre-zeroed)
{
    if (blockIdx.x < SHD_BLOCKS) {
        // ---- Shadow path: sorted zbuf -> early exit; benign-race stores ---
        const int Q = HWp / 4;
        const int t = blockIdx.x * 256 + threadIdx.x;  // < Q
        f32x4 z0 = __builtin_nontemporal_load(zb4 + t);  // k = 0 plane

        // k = 0: z0 - z0 = 0 < 0.1 always true -> just the sidx plane.
        {
            i32x4 si = __builtin_nontemporal_load(sidx4 + t);
            if (si.x >= 0) vis[si.x] = 1.0f;   // 2MB target stays in L2
            if (si.y >= 0) vis[si.y] = 1.0f;
            if (si.z >= 0) vis[si.z] = 1.0f;
            if (si.w >= 0) vis[si.w] = 1.0f;
        }

        for (int k = 1; k < KSp; ++k) {
            f32x4 z = __builtin_nontemporal_load(zb4 + k * Q + t);
            bool b0 = (z.x - z0.x) < 0.1f;
            bool b1 = (z.y - z0.y) < 0.1f;
            bool b2 = (z.z - z0.z) < 0.1f;
            bool b3 = (z.w - z0.w) < 0.1f;
            bool any = b0 | b1 | b2 | b3;
            if (any) {
                i32x4 si = __builtin_nontemporal_load(sidx4 + k * Q + t);
                if (b0 && si.x >= 0) vis[si.x] = 1.0f;
                if (b1 && si.y >= 0) vis[si.y] = 1.0f;
                if (b2 && si.z >= 0) vis[si.z] = 1.0f;
                if (b3 && si.w >= 0) vis[si.w] = 1.0f;
            }
            if (!__any(any)) break;  // zbuf sorted along k: monotone cond
        }
        return;  // whole block is shadow -> uniform exit, no syncthreads
    }

    // ---- Image path: per-pixel K-layer alpha composite, H-flipped output --
    const int p = (blockIdx.x - SHD_BLOCKS) * 256 + threadIdx.x;

    float acc[Cp];
#pragma unroll
    for (int c = 0; c < Cp; ++c) acc[c] = 0.0f;
    float T = 1.0f;

    for (int k = 0; k < Kp; ++k) {
        // Zero-reuse streams: nontemporal so they don't evict gather lines.
        int   i  = __builtin_nontemporal_load(idx + k * HWp + p);
        float d2 = __builtin_nontemporal_load(d2s + k * HWp + p);
        bool live = (i >= 0) && (T >= TCUT);
        if (live) {
            if (PACKED) {
                u32x4 r = packed[i];                 // one 16B gather
                float inv, _hi;
                unpack2(r.w >> 16, inv, _hi);        // fp16 bits in [31:16]
                float alpha = 1.0f - d2 * inv;
                float wgt   = alpha * T;
                T *= (1.0f - alpha);
                float wq = wgt * (1.0f / 255.0f);    // fold dequant scale
                acc[0]  += wq * (float)( r.x        & 0xff);
                acc[1]  += wq * (float)((r.x >>  8) & 0xff);
                acc[2]  += wq * (float)((r.x >> 16) & 0xff);
                acc[3]  += wq * (float)( r.x >> 24);
                acc[4]  += wq * (float)( r.y        & 0xff);
                acc[5]  += wq * (float)((r.y >>  8) & 0xff);
                acc[6]  += wq * (float)((r.y >> 16) & 0xff);
                acc[7]  += wq * (float)( r.y >> 24);
                acc[8]  += wq * (float)( r.z        & 0xff);
                acc[9]  += wq * (float)((r.z >>  8) & 0xff);
                acc[10] += wq * (float)((r.z >> 16) & 0xff);
                acc[11] += wq * (float)( r.z >> 24);
                acc[12] += wq * (float)( r.w        & 0xff);
                acc[13] += wq * (float)((r.w >>  8) & 0xff);
            } else {
                float f[Cp];
                const f32x2* s = feat2 + (long long)i * 7;
#pragma unroll
                for (int j = 0; j < 7; ++j) { f32x2 v = s[j]; f[2 * j] = v.x; f[2 * j + 1] = v.y; }
                float rr = rad[i];
                float inv = 1.0f / (rr * rr);
                float alpha = 1.0f - d2 * inv;
                float wgt   = alpha * T;
                T *= (1.0f - alpha);
#pragma unroll
                for (int c = 0; c < Cp; ++c) acc[c] += wgt * f[c];
            }
        }
        if (!__any(T >= TCUT)) break;  // whole wave dead -> stop streaming
    }

    // Stage 256 px x 14 f32 (14336 B) in LDS, then coalesced 16B nt stores.
    __shared__ __align__(16) float lds[256 * Cp];
    float* my = &lds[threadIdx.x * Cp];
#pragma unroll
    for (int j = 0; j < Cp; ++j) my[j] = acc[j];
    __syncthreads();

    const int base_pix = (blockIdx.x - SHD_BLOCKS) * 256;  // 256 px share h
    const int x0 = base_pix & (Wdim - 1);
    const int hb = base_pix >> 10;
    float* dst = out + ((long long)(Hdim - 1 - hb) * Wdim + x0) * Cp;  // H-flip
    u32x4* dst4 = (u32x4*)dst;                        // 3584 floats/block -> 16B aligned
    const u32x4* src4 = (const u32x4*)lds;
#pragma unroll
    for (int j = threadIdx.x; j < 256 * Cp / 4; j += 256)
        __builtin_nontemporal_store(src4[j], dst4 + j);  // write-once output
}

extern "C" void kernel_launch(void* const* d_in, const int* in_sizes, int n_in,
                              void* d_out, int out_size, void* d_ws, size_t ws_size,
                              hipStream_t stream)
{
    const int*   idx  = (const int*)d_in[0];
    const float* d2s  = (const float*)d_in[1];
    const int*   sidx = (const int*)d_in[2];
    const float* zbuf = (const float*)d_in[3];
    const float* rad  = (const float*)d_in[4];
    const float* feat = (const float*)d_in[5];

    float* out_img = (float*)d_out;
    float* out_vis = out_img + (long long)HWp * Cp;

    // visible starts at 0 (d_out is re-poisoned 0xAA before every launch)
    hipMemsetAsync(out_vis, 0, Np * sizeof(float), stream);

    const bool use_packed = ws_size >= (size_t)Np * 16;
    if (use_packed) {
        repack_k<<<(Np + 255) / 256, 256, 0, stream>>>(
            (const f32x2*)feat, rad, (u32x4*)d_ws);
        fused_k<true><<<SHD_BLOCKS + IMG_BLOCKS, 256, 0, stream>>>(
            idx, d2s, (const u32x4*)d_ws, nullptr, nullptr, out_img,
            (const i32x4*)sidx, (const f32x4*)zbuf, out_vis);
    } else {
        fused_k<false><<<SHD_BLOCKS + IMG_BLOCKS, 256, 0, stream>>>(
            idx, d2s, nullptr, (const f32x2*)feat, rad, out_img,
            (const i32x4*)sidx, (const f32x4*)zbuf, out_vis);
    }
}

// Round 6
// 540.438 us; speedup vs baseline: 1.0191x; 1.0191x over previous
//
#include <hip/hip_runtime.h>
#include <hip/hip_fp16.h>

// Native vector types: clang's __builtin_nontemporal_load/store only accept
// scalar/vector types, not HIP's struct float4.
typedef float        __attribute__((ext_vector_type(2))) f32x2;
typedef float        __attribute__((ext_vector_type(4))) f32x4;
typedef int          __attribute__((ext_vector_type(4))) i32x4;
typedef unsigned int __attribute__((ext_vector_type(4))) u32x4;

// Problem constants (from reference)
constexpr int Hdim = 1024;
constexpr int Wdim = 1024;
constexpr int HWp  = Hdim * Wdim;     // 1,048,576 pixels
constexpr int Kp   = 24;              // composite layers
constexpr int KSp  = 50;              // shadow layers
constexpr int Cp   = 14;              // feature channels
constexpr int Np   = 500000;          // points

// Early-exit transmittance cutoff. Remaining weights telescope to <= T and
// features are in [0,1), so per-channel truncation error <= TCUT.
// Empirical error model (verified to the ULP over rounds 2-5):
// absmax = TCUT + 2^-8 (harness compare is quantized at 2^-8).
// 8e-3 -> 0.0117 measured vs 2e-2 tolerance.
#define TCUT 8e-3f

// NOTE (round 5 lesson): do NOT fuse shadow_k into image_k. Co-residency
// amplifies vis writeback 57+2 -> 138 MB (scattered dirty lines evicted
// repeatedly under image's L2 pressure) and drops the gather rate
// 3.5 -> 3.3 TB/s (shadow streams steal per-XCD L2 capacity + MSHRs).
// Measured: fused 130.9 us vs ~97 us serial.

__device__ __forceinline__ unsigned pack2(float lo, float hi)
{
    __half2 h = __halves2half2(__float2half_rn(lo), __float2half_rn(hi));
    unsigned u; __builtin_memcpy(&u, &h, 4); return u;
}
__device__ __forceinline__ void unpack2(unsigned u, float& lo, float& hi)
{
    __half2 h; __builtin_memcpy(&h, &u, 4);
    lo = __low2float(h); hi = __high2float(h);
}

// ---- Pre-pass: features (N x 14 f32) -> u8 + fp16 1/r^2 in 16 B rows ------
// Gather table: 8 MB. 4 MB L2/XCD covers half -> ~50% L2 hit on random
// gathers (measured: R1's 16 MB table hit exactly the 4/16 capacity ratio,
// 64 B line granularity confirmed by bytes/gather arithmetic; L3 absorbs
// ~nothing). 8 B rows (full L2 residency) would need <=5-bit features ->
// error >= 0.016, over the budget. This is the table-size floor.
// Row layout (16 B): bytes 0..13 = u8 features (f = u8/255), bytes 14..15
// = fp16(1/r^2).
__global__ __launch_bounds__(256) void repack_k(
    const f32x2* __restrict__ feat2,   // N*7 float2 (56 B rows, 8B-aligned)
    const float* __restrict__ rad,     // N f32
    u32x4* __restrict__ ws)            // N u32x4 (16 B rows)
{
    int i = blockIdx.x * 256 + threadIdx.x;
    if (i >= Np) return;
    const f32x2* s = feat2 + (long long)i * 7;
    unsigned q[14];
#pragma unroll
    for (int j = 0; j < 7; ++j) {
        f32x2 v = __builtin_nontemporal_load(s + j);   // streamed once
        q[2 * j]     = (unsigned)(v.x * 255.0f + 0.5f);  // f in [0,1): exact rn
        q[2 * j + 1] = (unsigned)(v.y * 255.0f + 0.5f);
    }
    float r   = rad[i];
    float inv = 1.0f / (r * r);
    u32x4 w;
    w.x = q[0]  | (q[1]  << 8) | (q[2]  << 16) | (q[3]  << 24);
    w.y = q[4]  | (q[5]  << 8) | (q[6]  << 16) | (q[7]  << 24);
    w.z = q[8]  | (q[9]  << 8) | (q[10] << 16) | (q[11] << 24);
    w.w = q[12] | (q[13] << 8) | ((pack2(inv, 0.0f) & 0xffffu) << 16);
    ws[i] = w;
}

// ---- Image kernel: per-pixel K-layer alpha composite, H-flipped output ----
template <bool PACKED>
__global__ __launch_bounds__(256) void image_k(
    const int*   __restrict__ idx,     // (K, H, W) int32
    const float* __restrict__ d2s,     // (K, H, W) f32
    const u32x4* __restrict__ packed,  // N u32x4 (PACKED path)
    const f32x2* __restrict__ feat2,   // N*7 float2 (fallback path)
    const float* __restrict__ rad,     // N f32      (fallback path)
    float* __restrict__ out)           // (H, W, C) f32
{
    const int p = blockIdx.x * 256 + threadIdx.x;

    float acc[Cp];
#pragma unroll
    for (int c = 0; c < Cp; ++c) acc[c] = 0.0f;
    float T = 1.0f;

    for (int k = 0; k < Kp; ++k) {
        // Zero-reuse streams: nontemporal so they don't evict gather lines.
        int   i  = __builtin_nontemporal_load(idx + k * HWp + p);
        float d2 = __builtin_nontemporal_load(d2s + k * HWp + p);
        bool live = (i >= 0) && (T >= TCUT);
        if (live) {
            if (PACKED) {
                u32x4 r = packed[i];                 // one 16B gather
                float inv, _hi;
                unpack2(r.w >> 16, inv, _hi);        // fp16 bits in [31:16]
                float alpha = 1.0f - d2 * inv;
                float wgt   = alpha * T;
                T *= (1.0f - alpha);
                float wq = wgt * (1.0f / 255.0f);    // fold dequant scale
                acc[0]  += wq * (float)( r.x        & 0xff);
                acc[1]  += wq * (float)((r.x >>  8) & 0xff);
                acc[2]  += wq * (float)((r.x >> 16) & 0xff);
                acc[3]  += wq * (float)( r.x >> 24);
                acc[4]  += wq * (float)( r.y        & 0xff);
                acc[5]  += wq * (float)((r.y >>  8) & 0xff);
                acc[6]  += wq * (float)((r.y >> 16) & 0xff);
                acc[7]  += wq * (float)( r.y >> 24);
                acc[8]  += wq * (float)( r.z        & 0xff);
                acc[9]  += wq * (float)((r.z >>  8) & 0xff);
                acc[10] += wq * (float)((r.z >> 16) & 0xff);
                acc[11] += wq * (float)( r.z >> 24);
                acc[12] += wq * (float)( r.w        & 0xff);
                acc[13] += wq * (float)((r.w >>  8) & 0xff);
            } else {
                float f[Cp];
                const f32x2* s = feat2 + (long long)i * 7;
#pragma unroll
                for (int j = 0; j < 7; ++j) { f32x2 v = s[j]; f[2 * j] = v.x; f[2 * j + 1] = v.y; }
                float rr = rad[i];
                float inv = 1.0f / (rr * rr);
                float alpha = 1.0f - d2 * inv;
                float wgt   = alpha * T;
                T *= (1.0f - alpha);
#pragma unroll
                for (int c = 0; c < Cp; ++c) acc[c] += wgt * f[c];
            }
        }
        if (!__any(T >= TCUT)) break;  // whole wave dead -> stop streaming
    }

    // Stage 256 px x 14 f32 (14336 B) in LDS, then coalesced 16B nt stores.
    __shared__ __align__(16) float lds[256 * Cp];
    float* my = &lds[threadIdx.x * Cp];
#pragma unroll
    for (int j = 0; j < Cp; ++j) my[j] = acc[j];
    __syncthreads();

    const int base_pix = blockIdx.x * 256;           // all 256 px share h (W=1024)
    const int x0 = base_pix & (Wdim - 1);
    const int hb = base_pix >> 10;
    float* dst = out + ((long long)(Hdim - 1 - hb) * Wdim + x0) * Cp;  // H-flip
    u32x4* dst4 = (u32x4*)dst;                        // 3584 floats/block -> 16B aligned
    const u32x4* src4 = (const u32x4*)lds;
#pragma unroll
    for (int j = threadIdx.x; j < 256 * Cp / 4; j += 256)
        __builtin_nontemporal_store(src4[j], dst4 + j);  // write-once output
}

// ---- Shadow visibility: sorted zbuf -> early exit; benign-race 1.0 stores --
__global__ __launch_bounds__(256) void shadow_k(
    const i32x4* __restrict__ sidx4,  // (KS, HW/4) int4
    const f32x4* __restrict__ zb4,    // (KS, HW/4) float4
    float* __restrict__ vis)          // N f32 (pre-zeroed)
{
    const int Q = HWp / 4;
    const int t = blockIdx.x * 256 + threadIdx.x;  // < Q
    f32x4 z0 = __builtin_nontemporal_load(zb4 + t);  // k = 0 plane

    // k = 0: boundary condition z0 - z0 = 0 < 0.1 is always true -> no z
    // reload needed, just the sidx plane.
    {
        i32x4 si = __builtin_nontemporal_load(sidx4 + t);
        if (si.x >= 0) vis[si.x] = 1.0f;   // 2MB target stays in L2 (runs alone)
        if (si.y >= 0) vis[si.y] = 1.0f;
        if (si.z >= 0) vis[si.z] = 1.0f;
        if (si.w >= 0) vis[si.w] = 1.0f;
    }

    for (int k = 1; k < KSp; ++k) {
        f32x4 z = __builtin_nontemporal_load(zb4 + k * Q + t);
        bool b0 = (z.x - z0.x) < 0.1f;
        bool b1 = (z.y - z0.y) < 0.1f;
        bool b2 = (z.z - z0.z) < 0.1f;
        bool b3 = (z.w - z0.w) < 0.1f;
        bool any = b0 | b1 | b2 | b3;
        if (any) {
            i32x4 si = __builtin_nontemporal_load(sidx4 + k * Q + t);
            if (b0 && si.x >= 0) vis[si.x] = 1.0f;
            if (b1 && si.y >= 0) vis[si.y] = 1.0f;
            if (b2 && si.z >= 0) vis[si.z] = 1.0f;
            if (b3 && si.w >= 0) vis[si.w] = 1.0f;
        }
        if (!__any(any)) break;  // zbuf sorted along k: condition is monotone
    }
}

extern "C" void kernel_launch(void* const* d_in, const int* in_sizes, int n_in,
                              void* d_out, int out_size, void* d_ws, size_t ws_size,
                              hipStream_t stream)
{
    const int*   idx  = (const int*)d_in[0];
    const float* d2s  = (const float*)d_in[1];
    const int*   sidx = (const int*)d_in[2];
    const float* zbuf = (const float*)d_in[3];
    const float* rad  = (const float*)d_in[4];
    const float* feat = (const float*)d_in[5];

    float* out_img = (float*)d_out;
    float* out_vis = out_img + (long long)HWp * Cp;

    // visible starts at 0 (d_out is re-poisoned 0xAA before every launch)
    hipMemsetAsync(out_vis, 0, Np * sizeof(float), stream);

    const bool use_packed = ws_size >= (size_t)Np * 16;
    if (use_packed) {
        repack_k<<<(Np + 255) / 256, 256, 0, stream>>>(
            (const f32x2*)feat, rad, (u32x4*)d_ws);
        image_k<true><<<HWp / 256, 256, 0, stream>>>(
            idx, d2s, (const u32x4*)d_ws, nullptr, nullptr, out_img);
    } else {
        image_k<false><<<HWp / 256, 256, 0, stream>>>(
            idx, d2s, nullptr, (const f32x2*)feat, rad, out_img);
    }

    shadow_k<<<HWp / 4 / 256, 256, 0, stream>>>(
        (const i32x4*)sidx, (const f32x4*)zbuf, (float*)out_vis);
}